// Round 1
// baseline (985.360 us; speedup 1.0000x reference)
//
#include <hip/hip_runtime.h>
#include <math.h>

#define HW 16384   // 128*128
#define NB 4       // batch

__device__ __forceinline__ int imin(int a, int b) { return a < b ? a : b; }
__device__ __forceinline__ int imax(int a, int b) { return a > b ? a : b; }

// ---------------- transpose x (B,C,HW) -> xT (B,HW,C) ----------------
__global__ __launch_bounds__(256) void k_transpose(const float* __restrict__ x,
                                                   float* __restrict__ xT) {
  __shared__ float t[64][65];
  const int b = blockIdx.y;
  const int hw0 = blockIdx.x << 6;
  const int tid = threadIdx.x, lane = tid & 63, grp = tid >> 6;
#pragma unroll
  for (int r = 0; r < 16; ++r) {
    const int c = (grp << 4) + r;
    t[c][lane] = x[((b << 6) + c) * HW + hw0 + lane];
  }
  __syncthreads();
#pragma unroll
  for (int r = 0; r < 16; ++r) {
    const int hwl = (grp << 4) + r;
    xT[(b * HW + hw0 + hwl) * 64 + lane] = t[lane][hwl];
  }
}

// ---------------- pack weights ----------------
// wPack: [chunk 8][kk4 18][o 64][q 4], ck' = kk4*4+q, k = ck'>>3, cl = ck'&7, c = chunk*8+cl
// woPack: [c4 16][k 9][oc 27][cc 4] contiguous 432B slabs per (c4,k)
__global__ __launch_bounds__(256) void k_pack(const float* __restrict__ weight,
                                              const float* __restrict__ w_off,
                                              float* __restrict__ wPack,
                                              float* __restrict__ woPack) {
  const int g = blockIdx.x * 256 + threadIdx.x;
  if (g < 36864) {
    const int q = g & 3, o = (g >> 2) & 63, t = g >> 8;
    const int kk4 = t % 18, chunk = t / 18;
    const int ck = (kk4 << 2) + q, k = ck >> 3, cl = ck & 7, c = (chunk << 3) + cl;
    wPack[g] = weight[((o << 6) + c) * 9 + k];
  }
  if (g < 15552) {
    const int cc = g & 3, oc = (g >> 2) % 27, s = g / 108;
    const int k = s % 9, c4 = s / 9;
    woPack[g] = w_off[(((oc << 6) + (c4 << 2) + cc) * 9) + k];
  }
}

// ---------------- offset conv: xT -> offm[b][px][28] (18 offsets, 9 sigmoid mask) ----
__global__ __launch_bounds__(256) void k_offconv(const float* __restrict__ xT,
                                                 const float* __restrict__ woPack,
                                                 const float* __restrict__ b_off,
                                                 float* __restrict__ offm) {
  const int b = blockIdx.y;
  const int px0 = blockIdx.x << 6;
  const int tid = threadIdx.x;
  const int cg = tid >> 6, pxl = tid & 63;  // 4-way c split, 64 px
  const int px = px0 + pxl;
  const int h = px >> 7, w = px & 127;
  float acc[27];
#pragma unroll
  for (int i = 0; i < 27; ++i) acc[i] = 0.f;

  for (int c4 = cg << 2; c4 < (cg << 2) + 4; ++c4) {
#pragma unroll
    for (int k = 0; k < 9; ++k) {
      const int y = h + k / 3 - 1, xx = w + k % 3 - 1;
      float4 v = make_float4(0.f, 0.f, 0.f, 0.f);
      if (y >= 0 && y < 128 && xx >= 0 && xx < 128)
        v = *(const float4*)&xT[(b * HW + (y << 7) + xx) * 64 + (c4 << 2)];
      const float* wp = &woPack[(c4 * 9 + k) * 108];  // wave-uniform -> scalar loads
#pragma unroll
      for (int oc = 0; oc < 27; ++oc) {
        acc[oc] += v.x * wp[oc * 4 + 0] + v.y * wp[oc * 4 + 1] +
                   v.z * wp[oc * 4 + 2] + v.w * wp[oc * 4 + 3];
      }
    }
  }

  __shared__ float red[4][64][28];
#pragma unroll
  for (int oc = 0; oc < 27; ++oc) red[cg][pxl][oc] = acc[oc];
  __syncthreads();
  for (int e = tid; e < 64 * 27; e += 256) {
    const int p = e / 27, oc = e - p * 27;
    float s = red[0][p][oc] + red[1][p][oc] + red[2][p][oc] + red[3][p][oc] + b_off[oc];
    if (oc >= 18) s = 1.f / (1.f + expf(-s));
    offm[(b * HW + px0 + p) * 28 + oc] = s;
  }
}

// ---------------- deformable gather + contraction ----------------
// block: 64 px, 8 c-chunks of 8; val LDS [64 px][72(+4 pad)] (ck' = k*8+cl);
// GEMM: thread = (o = tid&63, pg = tid>>6) -> acc[16 px]
__global__ __launch_bounds__(256) void k_deform(const float* __restrict__ xT,
                                                const float* __restrict__ offm,
                                                const float* __restrict__ wPack,
                                                const float* __restrict__ bias,
                                                float* __restrict__ out) {
  __shared__ __align__(16) float vlds[64 * 76];
  __shared__ __align__(16) float wlds[18 * 64 * 4];
  const int b = blockIdx.y;
  const int px0 = blockIdx.x << 6;
  const int tid = threadIdx.x;

  // ---- per-pixel bilinear meta: 4 threads/px, k-sets {0,1,2},{3,4},{5,6},{7,8}
  const int pxl = tid >> 2, sub = tid & 3;
  const int pxm = px0 + pxl;
  const int h = pxm >> 7, w = pxm & 127;
  const int kbase = (sub == 0) ? 0 : (2 * sub + 1);
  const int nk = (sub == 0) ? 3 : 2;
  float wt[3][4];
  int cidx[3][4];
  {
    const float* om = &offm[(b * HW + pxm) * 28];
#pragma unroll
    for (int kk = 0; kk < 3; ++kk) {
      const int k = kbase + kk;
      const bool act = kk < nk;
      const float dy = act ? om[2 * k] : 0.f;
      const float dx = act ? om[2 * k + 1] : 0.f;
      const float m = act ? om[18 + k] : 0.f;
      const float py = (float)(h + k / 3 - 1) + dy;
      const float pxx = (float)(w + (k % 3) - 1) + dx;
      const float fy = floorf(py), fx = floorf(pxx);
      const int y0 = (int)fy, x0 = (int)fx;
      const int y1 = y0 + 1, x1 = x0 + 1;
      const float ly = py - fy, lx = pxx - fx;
      const bool vy0 = (y0 >= 0) && (y0 < 128), vy1 = (y1 >= 0) && (y1 < 128);
      const bool vx0 = (x0 >= 0) && (x0 < 128), vx1 = (x1 >= 0) && (x1 < 128);
      const int y0c = imin(imax(y0, 0), 127), y1c = imin(imax(y1, 0), 127);
      const int x0c = imin(imax(x0, 0), 127), x1c = imin(imax(x1, 0), 127);
      wt[kk][0] = (vy0 && vx0) ? (1.f - ly) * (1.f - lx) * m : 0.f;
      wt[kk][1] = (vy0 && vx1) ? (1.f - ly) * lx * m : 0.f;
      wt[kk][2] = (vy1 && vx0) ? ly * (1.f - lx) * m : 0.f;
      wt[kk][3] = (vy1 && vx1) ? ly * lx * m : 0.f;
      cidx[kk][0] = ((b * HW) + (y0c << 7) + x0c) << 6;
      cidx[kk][1] = ((b * HW) + (y0c << 7) + x1c) << 6;
      cidx[kk][2] = ((b * HW) + (y1c << 7) + x0c) << 6;
      cidx[kk][3] = ((b * HW) + (y1c << 7) + x1c) << 6;
    }
  }

  const int o = tid & 63, pg = tid >> 6;
  float acc[16];
#pragma unroll
  for (int i = 0; i < 16; ++i) acc[i] = 0.f;

  const float4* wp4 = (const float4*)wPack;
  float4* wlds4 = (float4*)wlds;

  for (int chunk = 0; chunk < 8; ++chunk) {
    const int c0 = chunk << 3;
    // stage weight chunk (72 ck' x 64 o)
    for (int i = tid; i < 1152; i += 256) wlds4[i] = wp4[chunk * 1152 + i];
    // gather 8 channels x my k's, premultiplied bilinear weights (mask+validity folded)
#pragma unroll
    for (int kk = 0; kk < 3; ++kk) {
      if (kk < nk) {
        const int k = kbase + kk;
        float4 va = make_float4(0.f, 0.f, 0.f, 0.f);
        float4 vb = make_float4(0.f, 0.f, 0.f, 0.f);
#pragma unroll
        for (int q = 0; q < 4; ++q) {
          const float wq = wt[kk][q];
          const float4* src = (const float4*)&xT[cidx[kk][q] + c0];
          const float4 a = src[0], bb = src[1];
          va.x += wq * a.x; va.y += wq * a.y; va.z += wq * a.z; va.w += wq * a.w;
          vb.x += wq * bb.x; vb.y += wq * bb.y; vb.z += wq * bb.z; vb.w += wq * bb.w;
        }
        const int vbi = pxl * 76 + (k << 3);
        *(float4*)&vlds[vbi] = va;
        *(float4*)&vlds[vbi + 4] = vb;
      }
    }
    __syncthreads();
    // contraction over this chunk's 72 ck'
    for (int kk4 = 0; kk4 < 18; ++kk4) {
      const float4 wv = *(const float4*)&wlds[(kk4 << 8) + (o << 2)];
#pragma unroll
      for (int p = 0; p < 16; ++p) {
        const float4 v = *(const float4*)&vlds[((pg << 4) + p) * 76 + (kk4 << 2)];
        acc[p] += wv.x * v.x + wv.y * v.y + wv.z * v.z + wv.w * v.w;
      }
    }
    __syncthreads();
  }

  const float bb = bias[o];
  float4* out4 = (float4*)out;
#pragma unroll
  for (int qq = 0; qq < 4; ++qq) {
    const float4 st = make_float4(acc[qq * 4 + 0] + bb, acc[qq * 4 + 1] + bb,
                                  acc[qq * 4 + 2] + bb, acc[qq * 4 + 3] + bb);
    out4[(((b << 6) + o) * HW + px0 + (pg << 4) + (qq << 2)) >> 2] = st;
  }
}

extern "C" void kernel_launch(void* const* d_in, const int* in_sizes, int n_in,
                              void* d_out, int out_size, void* d_ws, size_t ws_size,
                              hipStream_t stream) {
  (void)in_sizes; (void)n_in; (void)out_size; (void)ws_size;
  const float* x      = (const float*)d_in[0];
  const float* w_off  = (const float*)d_in[1];
  const float* b_off  = (const float*)d_in[2];
  const float* weight = (const float*)d_in[3];
  const float* bias   = (const float*)d_in[4];
  float* out = (float*)d_out;

  // workspace layout (floats): xT 4.19M | offm 1.84M | wPack 36864 | woPack 15552
  float* ws     = (float*)d_ws;
  float* xT     = ws;
  float* offm   = ws + 4194304;
  float* wPack  = offm + 1835008;
  float* woPack = wPack + 36864;

  k_transpose<<<dim3(256, NB), 256, 0, stream>>>(x, xT);
  k_pack<<<dim3(144), 256, 0, stream>>>(weight, w_off, wPack, woPack);
  k_offconv<<<dim3(256, NB), 256, 0, stream>>>(xT, woPack, b_off, offm);
  k_deform<<<dim3(256, NB), 256, 0, stream>>>(xT, offm, wPack, bias, out);
}

// Round 2
// 227.336 us; speedup vs baseline: 4.3344x; 4.3344x over previous
//
#include <hip/hip_runtime.h>
#include <math.h>

#define HW 16384   // 128*128
#define NB 4       // batch

__device__ __forceinline__ int imin(int a, int b) { return a < b ? a : b; }
__device__ __forceinline__ int imax(int a, int b) { return a > b ? a : b; }

// ---------------- transpose x (B,C,HW) -> xT (B,HW,C) ----------------
__global__ __launch_bounds__(256) void k_transpose(const float* __restrict__ x,
                                                   float* __restrict__ xT) {
  __shared__ float t[64][65];
  const int b = blockIdx.y;
  const int hw0 = blockIdx.x << 6;
  const int tid = threadIdx.x, lane = tid & 63, grp = tid >> 6;
#pragma unroll
  for (int r = 0; r < 16; ++r) {
    const int c = (grp << 4) + r;
    t[c][lane] = x[((b << 6) + c) * HW + hw0 + lane];
  }
  __syncthreads();
#pragma unroll
  for (int r = 0; r < 16; ++r) {
    const int hwl = (grp << 4) + r;
    xT[(b * HW + hw0 + hwl) * 64 + lane] = t[lane][hwl];
  }
}

// ---------------- pack weights ----------------
// wPack : [chunk 8][kk4 18][o 64][q 4], ck' = kk4*4+q, k = ck'>>3, cl = ck'&7, c = chunk*8+cl
// woPack2:[chunk 8][kk4 18][o 32][q 4], same ck' mapping; o>=27 rows are zero
__global__ __launch_bounds__(256) void k_pack(const float* __restrict__ weight,
                                              const float* __restrict__ w_off,
                                              float* __restrict__ wPack,
                                              float* __restrict__ woPack2) {
  const int g = blockIdx.x * 256 + threadIdx.x;
  if (g < 36864) {
    const int q = g & 3, o = (g >> 2) & 63, t = g >> 8;
    const int kk4 = t % 18, chunk = t / 18;
    const int ck = (kk4 << 2) + q, k = ck >> 3, cl = ck & 7, c = (chunk << 3) + cl;
    wPack[g] = weight[((o << 6) + c) * 9 + k];
  }
  if (g < 18432) {
    const int q = g & 3, o = (g >> 2) & 31, t = g >> 7;
    const int kk4 = t % 18, chunk = t / 18;
    const int ck = (kk4 << 2) + q, k = ck >> 3, cl = ck & 7, c = (chunk << 3) + cl;
    woPack2[g] = (o < 27) ? w_off[((o << 6) + c) * 9 + k] : 0.f;
  }
}

// ---------------- offset conv: xT -> offm[b][px][28] (18 offsets, 9 sigmoid mask) ----
// k_deform-style: per c-chunk LDS staging of shifted im2col values + weights.
// thread = (o = tid&31 [27 live], pg = tid>>5) -> acc[8 px]
__global__ __launch_bounds__(256) void k_offconv(const float* __restrict__ xT,
                                                 const float* __restrict__ woPack2,
                                                 const float* __restrict__ b_off,
                                                 float* __restrict__ offm) {
  __shared__ __align__(16) float vlds[64 * 76];
  __shared__ __align__(16) float wlds[18 * 32 * 4];
  const int b = blockIdx.y;
  const int px0 = blockIdx.x << 6;
  const int tid = threadIdx.x;

  // staging roles: 4 threads/px, k-sets {0,1,2},{3,4},{5,6},{7,8}
  const int pxl = tid >> 2, sub = tid & 3;
  const int px = px0 + pxl;
  const int h = px >> 7, w = px & 127;
  const int kbase = (sub == 0) ? 0 : (2 * sub + 1);
  const int nk = (sub == 0) ? 3 : 2;
  int cidx[3];
  bool vld[3];
#pragma unroll
  for (int kk = 0; kk < 3; ++kk) {
    const int k = kbase + kk;
    const int y = h + k / 3 - 1, xx = w + k % 3 - 1;
    vld[kk] = (kk < nk) && (y >= 0) && (y < 128) && (xx >= 0) && (xx < 128);
    const int yc = imin(imax(y, 0), 127), xc = imin(imax(xx, 0), 127);
    cidx[kk] = ((b * HW) + (yc << 7) + xc) << 6;
  }

  const int o = tid & 31, pg = tid >> 5;  // 8 px-groups of 8 px
  float acc[8];
#pragma unroll
  for (int i = 0; i < 8; ++i) acc[i] = 0.f;

  const float4* wp4 = (const float4*)woPack2;
  float4* wlds4 = (float4*)wlds;

  for (int chunk = 0; chunk < 8; ++chunk) {
    const int c0 = chunk << 3;
    // stage weight chunk (72 ck' x 32 o)
    for (int i = tid; i < 576; i += 256) wlds4[i] = wp4[chunk * 576 + i];
    // stage shifted im2col values (zero-padded)
#pragma unroll
    for (int kk = 0; kk < 3; ++kk) {
      if (kk < nk) {
        const int k = kbase + kk;
        float4 a = make_float4(0.f, 0.f, 0.f, 0.f);
        float4 bb = make_float4(0.f, 0.f, 0.f, 0.f);
        if (vld[kk]) {
          const float4* src = (const float4*)&xT[cidx[kk] + c0];
          a = src[0]; bb = src[1];
        }
        const int vbi = pxl * 76 + (k << 3);
        *(float4*)&vlds[vbi] = a;
        *(float4*)&vlds[vbi + 4] = bb;
      }
    }
    __syncthreads();
    for (int kk4 = 0; kk4 < 18; ++kk4) {
      const float4 wv = *(const float4*)&wlds[((kk4 << 5) + o) << 2];
#pragma unroll
      for (int p = 0; p < 8; ++p) {
        const float4 v = *(const float4*)&vlds[((pg << 3) + p) * 76 + (kk4 << 2)];
        acc[p] += wv.x * v.x + wv.y * v.y + wv.z * v.z + wv.w * v.w;
      }
    }
    __syncthreads();
  }

  if (o < 27) {
    const float bo = b_off[o];
#pragma unroll
    for (int p = 0; p < 8; ++p) {
      float s = acc[p] + bo;
      if (o >= 18) s = 1.f / (1.f + expf(-s));
      offm[(b * HW + px0 + (pg << 3) + p) * 28 + o] = s;
    }
  }
}

// ---------------- deformable gather + contraction ----------------
// block: 64 px, 8 c-chunks of 8; val LDS [64 px][72(+4 pad)] (ck' = k*8+cl);
// GEMM: thread = (o = tid&63, pg = tid>>6) -> acc[16 px]
__global__ __launch_bounds__(256) void k_deform(const float* __restrict__ xT,
                                                const float* __restrict__ offm,
                                                const float* __restrict__ wPack,
                                                const float* __restrict__ bias,
                                                float* __restrict__ out) {
  __shared__ __align__(16) float vlds[64 * 76];
  __shared__ __align__(16) float wlds[18 * 64 * 4];
  const int b = blockIdx.y;
  const int px0 = blockIdx.x << 6;
  const int tid = threadIdx.x;

  // ---- per-pixel bilinear meta: 4 threads/px, k-sets {0,1,2},{3,4},{5,6},{7,8}
  const int pxl = tid >> 2, sub = tid & 3;
  const int pxm = px0 + pxl;
  const int h = pxm >> 7, w = pxm & 127;
  const int kbase = (sub == 0) ? 0 : (2 * sub + 1);
  const int nk = (sub == 0) ? 3 : 2;
  float wt[3][4];
  int cidx[3][4];
  {
    const float* om = &offm[(b * HW + pxm) * 28];
#pragma unroll
    for (int kk = 0; kk < 3; ++kk) {
      const int k = kbase + kk;
      const bool act = kk < nk;
      const float dy = act ? om[2 * k] : 0.f;
      const float dx = act ? om[2 * k + 1] : 0.f;
      const float m = act ? om[18 + k] : 0.f;
      const float py = (float)(h + k / 3 - 1) + dy;
      const float pxx = (float)(w + (k % 3) - 1) + dx;
      const float fy = floorf(py), fx = floorf(pxx);
      const int y0 = (int)fy, x0 = (int)fx;
      const int y1 = y0 + 1, x1 = x0 + 1;
      const float ly = py - fy, lx = pxx - fx;
      const bool vy0 = (y0 >= 0) && (y0 < 128), vy1 = (y1 >= 0) && (y1 < 128);
      const bool vx0 = (x0 >= 0) && (x0 < 128), vx1 = (x1 >= 0) && (x1 < 128);
      const int y0c = imin(imax(y0, 0), 127), y1c = imin(imax(y1, 0), 127);
      const int x0c = imin(imax(x0, 0), 127), x1c = imin(imax(x1, 0), 127);
      wt[kk][0] = (vy0 && vx0) ? (1.f - ly) * (1.f - lx) * m : 0.f;
      wt[kk][1] = (vy0 && vx1) ? (1.f - ly) * lx * m : 0.f;
      wt[kk][2] = (vy1 && vx0) ? ly * (1.f - lx) * m : 0.f;
      wt[kk][3] = (vy1 && vx1) ? ly * lx * m : 0.f;
      cidx[kk][0] = ((b * HW) + (y0c << 7) + x0c) << 6;
      cidx[kk][1] = ((b * HW) + (y0c << 7) + x1c) << 6;
      cidx[kk][2] = ((b * HW) + (y1c << 7) + x0c) << 6;
      cidx[kk][3] = ((b * HW) + (y1c << 7) + x1c) << 6;
    }
  }

  const int o = tid & 63, pg = tid >> 6;
  float acc[16];
#pragma unroll
  for (int i = 0; i < 16; ++i) acc[i] = 0.f;

  const float4* wp4 = (const float4*)wPack;
  float4* wlds4 = (float4*)wlds;

  for (int chunk = 0; chunk < 8; ++chunk) {
    const int c0 = chunk << 3;
    // stage weight chunk (72 ck' x 64 o)
    for (int i = tid; i < 1152; i += 256) wlds4[i] = wp4[chunk * 1152 + i];
    // gather 8 channels x my k's, premultiplied bilinear weights (mask+validity folded)
#pragma unroll
    for (int kk = 0; kk < 3; ++kk) {
      if (kk < nk) {
        const int k = kbase + kk;
        float4 va = make_float4(0.f, 0.f, 0.f, 0.f);
        float4 vb = make_float4(0.f, 0.f, 0.f, 0.f);
#pragma unroll
        for (int q = 0; q < 4; ++q) {
          const float wq = wt[kk][q];
          const float4* src = (const float4*)&xT[cidx[kk][q] + c0];
          const float4 a = src[0], bb = src[1];
          va.x += wq * a.x; va.y += wq * a.y; va.z += wq * a.z; va.w += wq * a.w;
          vb.x += wq * bb.x; vb.y += wq * bb.y; vb.z += wq * bb.z; vb.w += wq * bb.w;
        }
        const int vbi = pxl * 76 + (k << 3);
        *(float4*)&vlds[vbi] = va;
        *(float4*)&vlds[vbi + 4] = vb;
      }
    }
    __syncthreads();
    // contraction over this chunk's 72 ck'
    for (int kk4 = 0; kk4 < 18; ++kk4) {
      const float4 wv = *(const float4*)&wlds[(kk4 << 8) + (o << 2)];
#pragma unroll
      for (int p = 0; p < 16; ++p) {
        const float4 v = *(const float4*)&vlds[((pg << 4) + p) * 76 + (kk4 << 2)];
        acc[p] += wv.x * v.x + wv.y * v.y + wv.z * v.z + wv.w * v.w;
      }
    }
    __syncthreads();
  }

  const float bb = bias[o];
  float4* out4 = (float4*)out;
#pragma unroll
  for (int qq = 0; qq < 4; ++qq) {
    const float4 st = make_float4(acc[qq * 4 + 0] + bb, acc[qq * 4 + 1] + bb,
                                  acc[qq * 4 + 2] + bb, acc[qq * 4 + 3] + bb);
    out4[(((b << 6) + o) * HW + px0 + (pg << 4) + (qq << 2)) >> 2] = st;
  }
}

extern "C" void kernel_launch(void* const* d_in, const int* in_sizes, int n_in,
                              void* d_out, int out_size, void* d_ws, size_t ws_size,
                              hipStream_t stream) {
  (void)in_sizes; (void)n_in; (void)out_size; (void)ws_size;
  const float* x      = (const float*)d_in[0];
  const float* w_off  = (const float*)d_in[1];
  const float* b_off  = (const float*)d_in[2];
  const float* weight = (const float*)d_in[3];
  const float* bias   = (const float*)d_in[4];
  float* out = (float*)d_out;

  // workspace layout (floats): xT 4.19M | offm 1.84M | wPack 36864 | woPack2 18432
  float* ws      = (float*)d_ws;
  float* xT      = ws;
  float* offm    = ws + 4194304;
  float* wPack   = offm + 1835008;
  float* woPack2 = wPack + 36864;

  k_transpose<<<dim3(256, NB), 256, 0, stream>>>(x, xT);
  k_pack<<<dim3(144), 256, 0, stream>>>(weight, w_off, wPack, woPack2);
  k_offconv<<<dim3(256, NB), 256, 0, stream>>>(xT, woPack2, b_off, offm);
  k_deform<<<dim3(256, NB), 256, 0, stream>>>(xT, offm, wPack, bias, out);
}

// Round 3
// 77.748 us; speedup vs baseline: 12.6738x; 2.9240x over previous
//
#include <hip/hip_runtime.h>
#include <math.h>

#define HW 16384   // 128*128
#define NB 4       // batch

typedef unsigned short u16;
typedef __bf16 bf16x8 __attribute__((ext_vector_type(8)));
typedef float f32x4 __attribute__((ext_vector_type(4)));

__device__ __forceinline__ int imin(int a, int b) { return a < b ? a : b; }
__device__ __forceinline__ int imax(int a, int b) { return a > b ? a : b; }
__device__ __forceinline__ float bl(unsigned u) { return __builtin_bit_cast(float, u << 16); }
__device__ __forceinline__ float bh(unsigned u) { return __builtin_bit_cast(float, u & 0xffff0000u); }
__device__ __forceinline__ u16 f2b(float f) { return __builtin_bit_cast(u16, (__bf16)f); }

// ---------------- transpose x (B,C,HW) f32 -> xTb (B,HW,C) bf16 ----------------
__global__ __launch_bounds__(256) void k_transpose(const float* __restrict__ x,
                                                   u16* __restrict__ xTb) {
  __shared__ float t[64][65];
  const int b = blockIdx.y;
  const int hw0 = blockIdx.x << 6;
  const int tid = threadIdx.x, lane = tid & 63, grp = tid >> 6;
#pragma unroll
  for (int r = 0; r < 16; ++r) {
    const int c = (grp << 4) + r;
    t[c][lane] = x[((b << 6) + c) * HW + hw0 + lane];
  }
  __syncthreads();
#pragma unroll
  for (int r = 0; r < 16; ++r) {
    const int hwl = (grp << 4) + r;
    xTb[(b * HW + hw0 + hwl) * 64 + lane] = f2b(t[lane][hwl]);
  }
}

// ---------------- pack weights to bf16, K(=c)-contiguous per tap ----------------
// wPackBf[k][o 64][c 64]; woBf[k][o 32 (27 live)][c 64]
__global__ __launch_bounds__(256) void k_pack(const float* __restrict__ weight,
                                              const float* __restrict__ w_off,
                                              u16* __restrict__ wPackBf,
                                              u16* __restrict__ woBf) {
  const int g = blockIdx.x * 256 + threadIdx.x;
  if (g < 36864) {
    const int k = g / 4096, rem = g & 4095, o = rem >> 6, c = rem & 63;
    wPackBf[g] = f2b(weight[(o * 64 + c) * 9 + k]);
  }
  if (g < 18432) {
    const int k = g / 2048, rem = g & 2047, o = rem >> 6, c = rem & 63;
    woBf[g] = (o < 27) ? f2b(w_off[(o * 64 + c) * 9 + k]) : (u16)0;
  }
}

// ---------------- offset conv via MFMA: xTb -> offmT[b][28][HW] ----------------
__global__ __launch_bounds__(256) void k_offconv(const u16* __restrict__ xTb,
                                                 const u16* __restrict__ woBf,
                                                 const float* __restrict__ b_off,
                                                 float* __restrict__ offmT) {
  __shared__ u16 wo[9 * 32 * 64];   // swizzled rows (row = k*32+o), 36864 B
  __shared__ u16 vlds[64 * 64];     // [px][c] swizzled, 8192 B
  __shared__ float slds[32][66];
  const int b = blockIdx.y, px0 = blockIdx.x << 6, tid = threadIdx.x;
  const int h = px0 >> 7, wbase = px0 & 127;
  const int lane = tid & 63, wv = tid >> 6;
  const int px_s = tid & 63, cg = tid >> 6;

  // stage all 9 taps of offset weights once (2304 uint4)
  const uint4* wg = (const uint4*)woBf;
  for (int u = tid; u < 2304; u += 256) {
    uint4 d = wg[u];
    const int byte = u << 4, row = u >> 3;
    *(uint4*)((char*)wo + (byte ^ ((row & 7) << 4))) = d;
  }

  // per-lane fragment address bases
  int rbA[2], szA[2];
#pragma unroll
  for (int i = 0; i < 2; ++i) {
    // row within wo for tap k added later as (k*32)*128 bytes
    const int rloc = i * 16 + (lane & 15);
    rbA[i] = rloc * 128 + ((lane >> 4) << 4);
    szA[i] = (rloc & 7) << 4;
  }
  const int rowB = wv * 16 + (lane & 15);
  const int rbB = rowB * 128 + ((lane >> 4) << 4);
  const int szB = (rowB & 7) << 4;

  f32x4 acc[2];
#pragma unroll
  for (int i = 0; i < 2; ++i) acc[i] = (f32x4)0.f;

  const int vb_lin = px_s * 128 + cg * 32;
  const int vswz = (px_s & 7) << 4;

  for (int k = 0; k < 9; ++k) {
    // stage shifted row (zero-padded)
    const int y = h + k / 3 - 1;
    const int xx = wbase + px_s + (k % 3) - 1;
    uint4 A = make_uint4(0, 0, 0, 0), B = make_uint4(0, 0, 0, 0);
    if (y >= 0 && y < 128 && xx >= 0 && xx < 128) {
      const uint4* s4 = (const uint4*)(xTb + ((b * HW + (y << 7) + xx) << 6) + (cg << 4));
      A = s4[0]; B = s4[1];
    }
    *(uint4*)((char*)vlds + (vb_lin ^ vswz)) = A;
    *(uint4*)((char*)vlds + ((vb_lin + 16) ^ vswz)) = B;
    __syncthreads();
    const int kbyte = k * 32 * 128;
#pragma unroll
    for (int s = 0; s < 2; ++s) {
      const bf16x8 bfr = *(const bf16x8*)((const char*)vlds + ((rbB + s * 64) ^ szB));
#pragma unroll
      for (int i = 0; i < 2; ++i) {
        const bf16x8 afr =
            *(const bf16x8*)((const char*)wo + ((kbyte + rbA[i] + s * 64) ^ szA[i]));
        acc[i] = __builtin_amdgcn_mfma_f32_16x16x32_bf16(afr, bfr, acc[i], 0, 0, 0);
      }
    }
    __syncthreads();
  }

  // epilogue: acc -> slds -> coalesced planes
#pragma unroll
  for (int i = 0; i < 2; ++i)
#pragma unroll
    for (int r = 0; r < 4; ++r)
      slds[i * 16 + ((lane >> 4) << 2) + r][wv * 16 + (lane & 15)] = acc[i][r];
  __syncthreads();
  for (int oc = cg; oc < 27; oc += 4) {
    float sv = slds[oc][px_s] + b_off[oc];
    if (oc >= 18) sv = 1.f / (1.f + expf(-sv));
    offmT[(b * 28 + oc) * HW + px0 + px_s] = sv;
  }
}

// ---------------- deformable gather + MFMA contraction ----------------
__global__ __launch_bounds__(256) void k_deform(const u16* __restrict__ xTb,
                                                const float* __restrict__ offmT,
                                                const u16* __restrict__ wPackBf,
                                                const float* __restrict__ bias,
                                                float* __restrict__ out) {
  __shared__ u16 wlds[64 * 64];       // [o][c] swizzled, 8192 B
  __shared__ u16 vlds[64 * 64];       // [px][c] swizzled, 8192 B
  __shared__ float mlds[9 * 64 * 9];  // per (tap,px): 4 wt, 4 cidx
  const int b = blockIdx.y, px0 = blockIdx.x << 6, tid = threadIdx.x;

  // ---- meta: 4 threads/px, k-sets {0,1,2},{3,4},{5,6},{7,8}
  {
    const int pxl = tid >> 2, sub = tid & 3;
    const int pxm = px0 + pxl;
    const int h = pxm >> 7, w = pxm & 127;
    const int kbase = (sub == 0) ? 0 : (2 * sub + 1);
    const int nk = (sub == 0) ? 3 : 2;
#pragma unroll
    for (int kk = 0; kk < 3; ++kk) {
      if (kk < nk) {
        const int k = kbase + kk;
        const float dy = offmT[(b * 28 + 2 * k) * HW + pxm];
        const float dx = offmT[(b * 28 + 2 * k + 1) * HW + pxm];
        const float m = offmT[(b * 28 + 18 + k) * HW + pxm];
        const float py = (float)(h + k / 3 - 1) + dy;
        const float pxx = (float)(w + (k % 3) - 1) + dx;
        const float fy = floorf(py), fx = floorf(pxx);
        const int y0 = (int)fy, x0 = (int)fx;
        const int y1 = y0 + 1, x1 = x0 + 1;
        const float ly = py - fy, lx = pxx - fx;
        const bool vy0 = (y0 >= 0) && (y0 < 128), vy1 = (y1 >= 0) && (y1 < 128);
        const bool vx0 = (x0 >= 0) && (x0 < 128), vx1 = (x1 >= 0) && (x1 < 128);
        const int y0c = imin(imax(y0, 0), 127), y1c = imin(imax(y1, 0), 127);
        const int x0c = imin(imax(x0, 0), 127), x1c = imin(imax(x1, 0), 127);
        float* mp = &mlds[(k * 64 + pxl) * 9];
        mp[0] = (vy0 && vx0) ? (1.f - ly) * (1.f - lx) * m : 0.f;
        mp[1] = (vy0 && vx1) ? (1.f - ly) * lx * m : 0.f;
        mp[2] = (vy1 && vx0) ? ly * (1.f - lx) * m : 0.f;
        mp[3] = (vy1 && vx1) ? ly * lx * m : 0.f;
        mp[4] = __int_as_float(((b * HW) + (y0c << 7) + x0c) << 6);
        mp[5] = __int_as_float(((b * HW) + (y0c << 7) + x1c) << 6);
        mp[6] = __int_as_float(((b * HW) + (y1c << 7) + x0c) << 6);
        mp[7] = __int_as_float(((b * HW) + (y1c << 7) + x1c) << 6);
      }
    }
  }
  __syncthreads();

  const int lane = tid & 63;
  const int ow = (tid >> 6) & 1, pw = tid >> 7;
  const int px_s = tid & 63, cg = tid >> 6;

  int rbA[2], szA[2], rbB[2], szB[2];
#pragma unroll
  for (int i = 0; i < 2; ++i) {
    const int rowA = ow * 32 + i * 16 + (lane & 15);
    rbA[i] = rowA * 128 + ((lane >> 4) << 4);
    szA[i] = (rowA & 7) << 4;
    const int rowB = pw * 32 + i * 16 + (lane & 15);
    rbB[i] = rowB * 128 + ((lane >> 4) << 4);
    szB[i] = (rowB & 7) << 4;
  }
  const int vb_lin = px_s * 128 + cg * 32;
  const int vswz = (px_s & 7) << 4;

  f32x4 acc[2][2];
#pragma unroll
  for (int i = 0; i < 2; ++i)
#pragma unroll
    for (int j = 0; j < 2; ++j) acc[i][j] = (f32x4)0.f;

  for (int k = 0; k < 9; ++k) {
    // stage weights for tap k (512 uint4)
    const uint4* wg = (const uint4*)(wPackBf + (k << 12));
#pragma unroll
    for (int u = 0; u < 2; ++u) {
      const int id = tid + (u << 8);
      uint4 d = wg[id];
      const int byte = id << 4, row = id >> 3;
      *(uint4*)((char*)wlds + (byte ^ ((row & 7) << 4))) = d;
    }
    // gather + weighted corner sum -> bf16 vlds
    const float* mp = &mlds[(k * 64 + px_s) * 9];
    float wt[4];
    int ci[4];
#pragma unroll
    for (int q = 0; q < 4; ++q) { wt[q] = mp[q]; ci[q] = __float_as_int(mp[4 + q]); }
    float va[16];
#pragma unroll
    for (int j = 0; j < 16; ++j) va[j] = 0.f;
#pragma unroll
    for (int q = 0; q < 4; ++q) {
      const float wq = wt[q];
      const uint4* s4 = (const uint4*)(xTb + ci[q] + (cg << 4));
      const uint4 A = s4[0], B = s4[1];
      const unsigned uu[8] = {A.x, A.y, A.z, A.w, B.x, B.y, B.z, B.w};
#pragma unroll
      for (int j = 0; j < 8; ++j) {
        va[2 * j] += wq * bl(uu[j]);
        va[2 * j + 1] += wq * bh(uu[j]);
      }
    }
    unsigned pk[8];
#pragma unroll
    for (int j = 0; j < 8; ++j)
      pk[j] = (unsigned)f2b(va[2 * j]) | ((unsigned)f2b(va[2 * j + 1]) << 16);
    *(uint4*)((char*)vlds + (vb_lin ^ vswz)) = make_uint4(pk[0], pk[1], pk[2], pk[3]);
    *(uint4*)((char*)vlds + ((vb_lin + 16) ^ vswz)) = make_uint4(pk[4], pk[5], pk[6], pk[7]);
    __syncthreads();
#pragma unroll
    for (int s = 0; s < 2; ++s) {
      bf16x8 af[2], bf_[2];
#pragma unroll
      for (int t = 0; t < 2; ++t) {
        af[t] = *(const bf16x8*)((const char*)wlds + ((rbA[t] + s * 64) ^ szA[t]));
        bf_[t] = *(const bf16x8*)((const char*)vlds + ((rbB[t] + s * 64) ^ szB[t]));
      }
#pragma unroll
      for (int i = 0; i < 2; ++i)
#pragma unroll
        for (int j = 0; j < 2; ++j)
          acc[i][j] = __builtin_amdgcn_mfma_f32_16x16x32_bf16(af[i], bf_[j], acc[i][j], 0, 0, 0);
    }
    __syncthreads();
  }

  // epilogue: direct stores (per 16-lane group: 64B contiguous px)
#pragma unroll
  for (int i = 0; i < 2; ++i)
#pragma unroll
    for (int r = 0; r < 4; ++r) {
      const int o = ow * 32 + i * 16 + ((lane >> 4) << 2) + r;
      const float bv = bias[o];
#pragma unroll
      for (int j = 0; j < 2; ++j)
        out[(b * 64 + o) * HW + px0 + pw * 32 + j * 16 + (lane & 15)] = acc[i][j][r] + bv;
    }
}

extern "C" void kernel_launch(void* const* d_in, const int* in_sizes, int n_in,
                              void* d_out, int out_size, void* d_ws, size_t ws_size,
                              hipStream_t stream) {
  (void)in_sizes; (void)n_in; (void)out_size; (void)ws_size;
  const float* x      = (const float*)d_in[0];
  const float* w_off  = (const float*)d_in[1];
  const float* b_off  = (const float*)d_in[2];
  const float* weight = (const float*)d_in[3];
  const float* bias   = (const float*)d_in[4];
  float* out = (float*)d_out;

  char* wsb = (char*)d_ws;
  u16* xTb     = (u16*)wsb;                                    // 8,388,608 B
  float* offmT = (float*)(wsb + 8388608);                      // 7,340,032 B
  u16* wPackBf = (u16*)(wsb + 8388608 + 7340032);              // 73,728 B
  u16* woBf    = (u16*)(wsb + 8388608 + 7340032 + 73728);      // 36,864 B

  k_transpose<<<dim3(256, NB), 256, 0, stream>>>(x, xTb);
  k_pack<<<dim3(144), 256, 0, stream>>>(weight, w_off, wPackBf, woBf);
  k_offconv<<<dim3(256, NB), 256, 0, stream>>>(xTb, woBf, b_off, offmT);
  k_deform<<<dim3(256, NB), 256, 0, stream>>>(xTb, offmT, wPackBf, bias, out);
}

// Round 4
// 64.725 us; speedup vs baseline: 15.2238x; 1.2012x over previous
//
#include <hip/hip_runtime.h>
#include <math.h>

#define HW 16384   // 128*128
#define NB 4       // batch

typedef unsigned short u16;
typedef _Float16 f16x8 __attribute__((ext_vector_type(8)));
typedef _Float16 f16x2 __attribute__((ext_vector_type(2)));
typedef float f32x4 __attribute__((ext_vector_type(4)));

__device__ __forceinline__ int imin(int a, int b) { return a < b ? a : b; }
__device__ __forceinline__ int imax(int a, int b) { return a > b ? a : b; }
__device__ __forceinline__ u16 f2h(float f) {
  _Float16 h = (_Float16)f;
  return __builtin_bit_cast(u16, h);
}
// async global->LDS, 16B per lane; l must be wave-uniform base (lane*16 implicit)
__device__ __forceinline__ void gld16(const u16* g, u16* l) {
  __builtin_amdgcn_global_load_lds((const __attribute__((address_space(1))) void*)g,
                                   (__attribute__((address_space(3))) void*)l, 16, 0, 0);
}

// ---------------- transpose x (B,C,HW) f32 -> xTh (B,HW,C) f16 ----------------
__global__ __launch_bounds__(256) void k_transpose(const float* __restrict__ x,
                                                   u16* __restrict__ xTh) {
  __shared__ float t[64][65];
  const int b = blockIdx.y;
  const int hw0 = blockIdx.x << 6;
  const int tid = threadIdx.x, lane = tid & 63, grp = tid >> 6;
#pragma unroll
  for (int r = 0; r < 16; ++r) {
    const int c = (grp << 4) + r;
    t[c][lane] = x[((b << 6) + c) * HW + hw0 + lane];
  }
  __syncthreads();
#pragma unroll
  for (int r = 0; r < 16; ++r) {
    const int hwl = (grp << 4) + r;
    xTh[(b * HW + hw0 + hwl) * 64 + lane] = f2h(t[lane][hwl]);
  }
}

// ---------------- pack weights to f16, pre-swizzled rows (XOR c ^ ((o&7)<<3)) ----
// wSwz [k 9][o 64][c'64] ; woSwz [k 9][o 32 (27 live)][c'64] ; zpage 512 zeros
__global__ __launch_bounds__(256) void k_pack(const float* __restrict__ weight,
                                              const float* __restrict__ w_off,
                                              u16* __restrict__ wSwz,
                                              u16* __restrict__ woSwz,
                                              u16* __restrict__ zpage) {
  const int g = blockIdx.x * 256 + threadIdx.x;
  if (g < 36864) {
    const int k = g / 4096, rem = g & 4095, o = rem >> 6, c = rem & 63;
    wSwz[k * 4096 + (o << 6) + (c ^ ((o & 7) << 3))] = f2h(weight[((o << 6) + c) * 9 + k]);
  }
  if (g < 18432) {
    const int k = g / 2048, rem = g & 2047, o = rem >> 6, c = rem & 63;
    woSwz[k * 2048 + (o << 6) + (c ^ ((o & 7) << 3))] =
        (o < 27) ? f2h(w_off[((o << 6) + c) * 9 + k]) : (u16)0;
  }
  if (g < 512) zpage[g] = 0;
}

// ---------------- offset conv via MFMA, pipelined gl_lds staging ----------------
__global__ __launch_bounds__(256, 4) void k_offconv(const u16* __restrict__ xTh,
                                                    const u16* __restrict__ woSwz,
                                                    const u16* __restrict__ zpage,
                                                    const float* __restrict__ b_off,
                                                    float* __restrict__ offmT) {
  __shared__ u16 wo[2][2048];   // 4096 B per buf (32 o rows x 128 B)
  __shared__ u16 vl[2][4096];   // 8192 B per buf (64 px rows x 128 B)
  __shared__ float slds[32][66];
  const int b = blockIdx.y, px0 = blockIdx.x << 6, tid = threadIdx.x;
  const int lane = tid & 63, wv = tid >> 6;
  const int hrow = px0 >> 7, wbase = px0 & 127;

  int rbA[2], szA[2];
#pragma unroll
  for (int i = 0; i < 2; ++i) {
    const int rowA = i * 16 + (lane & 15);
    rbA[i] = rowA * 128 + ((lane >> 4) << 4);
    szA[i] = (rowA & 7) << 4;
  }
  const int rowB = wv * 16 + (lane & 15);
  const int rbB = rowB * 128 + ((lane >> 4) << 4);
  const int szB = (rowB & 7) << 4;

  auto stage = [&](int k, int buf) {
    // weights: contiguous pre-swizzled copy (1 gl_lds/thread)
    gld16(woSwz + k * 2048 + (tid << 3), &wo[buf][wv << 9]);
    // shifted row: per-lane source w/ zero-page redirect + source-side swizzle
    const int y = hrow + k / 3 - 1;
    const int kj = k % 3 - 1;
#pragma unroll
    for (int u = 0; u < 2; ++u) {
      const int idx16 = (wv << 7) + (u << 6) + lane;
      const int px = idx16 >> 3, seg = idx16 & 7;
      const int xx = wbase + px + kj;
      const u16* src;
      if (y < 0 || y > 127 || xx < 0 || xx > 127)
        src = zpage + (lane << 3);
      else
        src = xTh + ((b * HW + (y << 7) + xx) << 6) + ((seg << 3) ^ ((px & 7) << 3));
      gld16(src, &vl[buf][(wv << 10) + (u << 9)]);
    }
  };

  f32x4 acc[2];
#pragma unroll
  for (int i = 0; i < 2; ++i) acc[i] = (f32x4)0.f;

  stage(0, 0);
  __syncthreads();

#pragma unroll 1
  for (int k = 0; k < 9; ++k) {
    if (k < 8) stage(k + 1, (k + 1) & 1);
    const char* wbuf = (const char*)wo[k & 1];
    const char* vbuf = (const char*)vl[k & 1];
#pragma unroll
    for (int s = 0; s < 2; ++s) {
      const f16x8 bfr = *(const f16x8*)(vbuf + ((rbB + s * 64) ^ szB));
#pragma unroll
      for (int i = 0; i < 2; ++i) {
        const f16x8 afr = *(const f16x8*)(wbuf + ((rbA[i] + s * 64) ^ szA[i]));
        acc[i] = __builtin_amdgcn_mfma_f32_16x16x32_f16(afr, bfr, acc[i], 0, 0, 0);
      }
    }
    __syncthreads();
  }

  // epilogue: transpose via slds, bias+sigmoid, coalesced plane writes
#pragma unroll
  for (int i = 0; i < 2; ++i)
#pragma unroll
    for (int r = 0; r < 4; ++r)
      slds[i * 16 + ((lane >> 4) << 2) + r][wv * 16 + (lane & 15)] = acc[i][r];
  __syncthreads();
  for (int oc = wv; oc < 27; oc += 4) {
    float sv = slds[oc][lane] + b_off[oc];
    if (oc >= 18) sv = 1.f / (1.f + expf(-sv));
    offmT[(b * 28 + oc) * HW + px0 + lane] = sv;
  }
}

// ---------------- deformable gather + MFMA, software-pipelined ----------------
__global__ __launch_bounds__(256, 4) void k_deform(const u16* __restrict__ xTh,
                                                   const float* __restrict__ offmT,
                                                   const u16* __restrict__ wSwz,
                                                   const float* __restrict__ bias,
                                                   float* __restrict__ out) {
  __shared__ u16 wl[2][4096];  // 8192 B per buf (64 o rows x 128 B)
  __shared__ u16 vl[2][4096];  // 8192 B per buf (64 px rows x 128 B)
  const int b = blockIdx.y, px0 = blockIdx.x << 6, tid = threadIdx.x;
  const int lane = tid & 63, wv = tid >> 6;
  const int px_s = lane, cg = wv;          // staging role: pixel, 16-ch group
  const int ow = wv & 1, pw = wv >> 1;     // mfma role
  const int hh = (px0 + px_s) >> 7, ww = (px0 + px_s) & 127;
  const float* omb = offmT + b * 28 * HW + px0 + px_s;

  int rbA[2], szA[2], rbB[2], szB[2];
#pragma unroll
  for (int i = 0; i < 2; ++i) {
    const int rowA = ow * 32 + i * 16 + (lane & 15);
    rbA[i] = rowA * 128 + ((lane >> 4) << 4);
    szA[i] = (rowA & 7) << 4;
    const int rowB = pw * 32 + i * 16 + (lane & 15);
    rbB[i] = rowB * 128 + ((lane >> 4) << 4);
    szB[i] = (rowB & 7) << 4;
  }
  const int vb0 = px_s * 128 + cg * 32;
  const int vsw = (px_s & 7) << 4;

  f32x4 acc[2][2];
#pragma unroll
  for (int i = 0; i < 2; ++i)
#pragma unroll
    for (int j = 0; j < 2; ++j) acc[i][j] = (f32x4)0.f;

  float o3[3];
  float wt[4];
  int ci[4];
  uint4 g[8];

  auto load3 = [&](int k, float* d) {
    d[0] = omb[(2 * k) * HW];
    d[1] = omb[(2 * k + 1) * HW];
    d[2] = omb[(18 + k) * HW];
  };
  auto meta = [&](int k, const float* d) {
    const float py = (float)(hh + k / 3 - 1) + d[0];
    const float pxx = (float)(ww + k % 3 - 1) + d[1];
    const float m = d[2];
    const float fy = floorf(py), fx = floorf(pxx);
    const int y0 = (int)fy, x0 = (int)fx;
    const int y1 = y0 + 1, x1 = x0 + 1;
    const float ly = py - fy, lx = pxx - fx;
    const bool vy0 = (y0 >= 0) && (y0 < 128), vy1 = (y1 >= 0) && (y1 < 128);
    const bool vx0 = (x0 >= 0) && (x0 < 128), vx1 = (x1 >= 0) && (x1 < 128);
    const int y0c = imin(imax(y0, 0), 127), y1c = imin(imax(y1, 0), 127);
    const int x0c = imin(imax(x0, 0), 127), x1c = imin(imax(x1, 0), 127);
    wt[0] = (vy0 && vx0) ? (1.f - ly) * (1.f - lx) * m : 0.f;
    wt[1] = (vy0 && vx1) ? (1.f - ly) * lx * m : 0.f;
    wt[2] = (vy1 && vx0) ? ly * (1.f - lx) * m : 0.f;
    wt[3] = (vy1 && vx1) ? ly * lx * m : 0.f;
    ci[0] = (((b * HW) + (y0c << 7) + x0c) << 6) + (cg << 4);
    ci[1] = (((b * HW) + (y0c << 7) + x1c) << 6) + (cg << 4);
    ci[2] = (((b * HW) + (y1c << 7) + x0c) << 6) + (cg << 4);
    ci[3] = (((b * HW) + (y1c << 7) + x1c) << 6) + (cg << 4);
  };
  auto gather = [&]() {
#pragma unroll
    for (int q = 0; q < 4; ++q) {
      const uint4* s = (const uint4*)(xTh + ci[q]);
      g[2 * q] = s[0];
      g[2 * q + 1] = s[1];
    }
  };
  auto stage_w = [&](int k, u16* wbuf) {
#pragma unroll
    for (int u = 0; u < 2; ++u)
      gld16(wSwz + k * 4096 + (wv << 10) + (u << 9) + (lane << 3),
            wbuf + (wv << 10) + (u << 9));
  };
  auto blend_store = [&](u16* vbuf) {
    f16x2 va[8];
#pragma unroll
    for (int j = 0; j < 8; ++j) va[j] = (f16x2)(_Float16)0.f;
#pragma unroll
    for (int q = 0; q < 4; ++q) {
      f16x2 w2;
      w2[0] = w2[1] = (_Float16)wt[q];
      const uint4 A = g[2 * q], B = g[2 * q + 1];
      const unsigned uu[8] = {A.x, A.y, A.z, A.w, B.x, B.y, B.z, B.w};
#pragma unroll
      for (int j = 0; j < 8; ++j)
        va[j] = __builtin_elementwise_fma(__builtin_bit_cast(f16x2, uu[j]), w2, va[j]);
    }
    uint4 pa, pb;
    pa.x = __builtin_bit_cast(unsigned, va[0]); pa.y = __builtin_bit_cast(unsigned, va[1]);
    pa.z = __builtin_bit_cast(unsigned, va[2]); pa.w = __builtin_bit_cast(unsigned, va[3]);
    pb.x = __builtin_bit_cast(unsigned, va[4]); pb.y = __builtin_bit_cast(unsigned, va[5]);
    pb.z = __builtin_bit_cast(unsigned, va[6]); pb.w = __builtin_bit_cast(unsigned, va[7]);
    *(uint4*)((char*)vbuf + (vb0 ^ vsw)) = pa;
    *(uint4*)((char*)vbuf + ((vb0 + 16) ^ vsw)) = pb;
  };

  // ---- prologue: fill tap 0, prefetch offm(1)
  load3(0, o3);
  meta(0, o3);
  gather();
  stage_w(0, wl[0]);
  blend_store(vl[0]);
  load3(1, o3);
  __syncthreads();

#pragma unroll 1
  for (int k = 0; k < 9; ++k) {
    float onx[3];
    const bool more = k < 8;
    if (more) {
      if (k < 7) load3(k + 2, onx);   // offm prefetch, 2 taps ahead
      meta(k + 1, o3);
      gather();                       // corner loads in flight across MFMA
      stage_w(k + 1, wl[(k + 1) & 1]);
    }
    const char* wbuf = (const char*)wl[k & 1];
    const char* vbuf = (const char*)vl[k & 1];
#pragma unroll
    for (int s = 0; s < 2; ++s) {
      f16x8 af[2], bfr[2];
#pragma unroll
      for (int t = 0; t < 2; ++t) {
        af[t] = *(const f16x8*)(wbuf + ((rbA[t] + s * 64) ^ szA[t]));
        bfr[t] = *(const f16x8*)(vbuf + ((rbB[t] + s * 64) ^ szB[t]));
      }
#pragma unroll
      for (int i = 0; i < 2; ++i)
#pragma unroll
        for (int j = 0; j < 2; ++j)
          acc[i][j] = __builtin_amdgcn_mfma_f32_16x16x32_f16(af[i], bfr[j], acc[i][j], 0, 0, 0);
    }
    if (more) {
      blend_store(vl[(k + 1) & 1]);
      o3[0] = onx[0]; o3[1] = onx[1]; o3[2] = onx[2];
    }
    __syncthreads();
  }

  // epilogue: direct stores
#pragma unroll
  for (int i = 0; i < 2; ++i)
#pragma unroll
    for (int r = 0; r < 4; ++r) {
      const int o = ow * 32 + i * 16 + ((lane >> 4) << 2) + r;
      const float bv = bias[o];
#pragma unroll
      for (int j = 0; j < 2; ++j)
        out[(b * 64 + o) * HW + px0 + pw * 32 + j * 16 + (lane & 15)] = acc[i][j][r] + bv;
    }
}

extern "C" void kernel_launch(void* const* d_in, const int* in_sizes, int n_in,
                              void* d_out, int out_size, void* d_ws, size_t ws_size,
                              hipStream_t stream) {
  (void)in_sizes; (void)n_in; (void)out_size; (void)ws_size;
  const float* x      = (const float*)d_in[0];
  const float* w_off  = (const float*)d_in[1];
  const float* b_off  = (const float*)d_in[2];
  const float* weight = (const float*)d_in[3];
  const float* bias   = (const float*)d_in[4];
  float* out = (float*)d_out;

  char* wsb = (char*)d_ws;
  u16* xTh     = (u16*)wsb;                       // 8,388,608 B
  float* offmT = (float*)(wsb + 8388608);         // 7,340,032 B
  u16* wSwz    = (u16*)(wsb + 15728640);          // 73,728 B
  u16* woSwz   = (u16*)(wsb + 15802368);          // 36,864 B
  u16* zpage   = (u16*)(wsb + 15839232);          // 1,024 B

  k_transpose<<<dim3(256, NB), 256, 0, stream>>>(x, xTh);
  k_pack<<<dim3(144), 256, 0, stream>>>(weight, w_off, wSwz, woSwz, zpage);
  k_offconv<<<dim3(256, NB), 256, 0, stream>>>(xTh, woSwz, zpage, b_off, offmT);
  k_deform<<<dim3(256, NB), 256, 0, stream>>>(xTh, offmT, wSwz, bias, out);
}